// Round 3
// baseline (12178.225 us; speedup 1.0000x reference)
//
#include <hip/hip_runtime.h>
#include <stdint.h>

// BasicNCA2D: 10 steps of depthwise7x7(reflect) -> concat -> fc0 -> BN(batch) -> relu -> fc1 -> masked update.
// B=8,H=256,W=256,C=16,HID=128. steps hardcoded to 10.
// RNG: JAX threefry, jax_threefry_partitionable=True: bits[i] = xor(threefry2x32(key,(0,i))).
//
// R2: all weights (conv/fc0T/fc1/scale-shift) read from GLOBAL with block-uniform
// indices -> compiler emits s_load into SGPRs (scalar pipe), eliminating the LDS
// weight reads that capped nca_update at VALUBusy 44% (12 ds_read_b128 per hid iter).
// nca_update now uses zero LDS. fc0 weights pre-transposed to hid-major once per launch.

constexpr int Bn = 8;
constexpr int Hn = 256;
constexpr int Wn = 256;
constexpr int Cn = 16;
constexpr int HIDn = 128;
constexpr int NROW = Bn * Hn;              // 2048 (b,h) rows, one block each
constexpr int NCELLS = Bn * Hn * Wn;       // 524288
constexpr int NPAIR = 528;                 // 32*33/2 unique second moments of y
constexpr int NSTAT = 560;                 // pairs + 32 first moments
constexpr int STEPS = 10;

__host__ __device__ inline uint32_t rotl32(uint32_t v, int r) {
  return (v << r) | (v >> (32 - r));
}

// Threefry-2x32, 20 rounds, exactly as jax/_src/prng.py
__host__ __device__ inline void tf2x32(uint32_t k0, uint32_t k1,
                                       uint32_t& x0, uint32_t& x1) {
  uint32_t k2 = k0 ^ k1 ^ 0x1BD11BDAu;
  x0 += k0; x1 += k1;
  x0 += x1; x1 = rotl32(x1, 13); x1 ^= x0;
  x0 += x1; x1 = rotl32(x1, 15); x1 ^= x0;
  x0 += x1; x1 = rotl32(x1, 26); x1 ^= x0;
  x0 += x1; x1 = rotl32(x1,  6); x1 ^= x0;
  x0 += k1; x1 += k2 + 1u;
  x0 += x1; x1 = rotl32(x1, 17); x1 ^= x0;
  x0 += x1; x1 = rotl32(x1, 29); x1 ^= x0;
  x0 += x1; x1 = rotl32(x1, 16); x1 ^= x0;
  x0 += x1; x1 = rotl32(x1, 24); x1 ^= x0;
  x0 += k2; x1 += k0 + 2u;
  x0 += x1; x1 = rotl32(x1, 13); x1 ^= x0;
  x0 += x1; x1 = rotl32(x1, 15); x1 ^= x0;
  x0 += x1; x1 = rotl32(x1, 26); x1 ^= x0;
  x0 += x1; x1 = rotl32(x1,  6); x1 ^= x0;
  x0 += k0; x1 += k1 + 3u;
  x0 += x1; x1 = rotl32(x1, 17); x1 ^= x0;
  x0 += x1; x1 = rotl32(x1, 29); x1 ^= x0;
  x0 += x1; x1 = rotl32(x1, 16); x1 ^= x0;
  x0 += x1; x1 = rotl32(x1, 24); x1 ^= x0;
  x0 += k1; x1 += k2 + 4u;
  x0 += x1; x1 = rotl32(x1, 13); x1 ^= x0;
  x0 += x1; x1 = rotl32(x1, 15); x1 ^= x0;
  x0 += x1; x1 = rotl32(x1, 26); x1 ^= x0;
  x0 += x1; x1 = rotl32(x1,  6); x1 ^= x0;
  x0 += k2; x1 += k0 + 5u;
}

__device__ inline float cell_mask(uint32_t fk0, uint32_t fk1, uint32_t ci) {
  uint32_t a = 0u, b2 = ci;
  tf2x32(fk0, fk1, a, b2);
  uint32_t bits = a ^ b2;
  float u = __uint_as_float((bits >> 9) | 0x3f800000u) - 1.0f;
  return (u > 0.5f) ? 1.0f : 0.0f;
}

// depthwise 7x7 reflect conv for one cell; weights read from GLOBAL with uniform
// index (s_load). Also returns center x values.
__device__ inline void conv_cell(const float* __restrict__ xb, int hr, int w,
                                 const float* __restrict__ p0w,
                                 float conv[16], float xc[16]) {
#pragma unroll
  for (int c = 0; c < 16; c++) conv[c] = 0.0f;
#pragma unroll
  for (int dy = 0; dy < 7; dy++) {
    int hh = hr + dy - 3;
    hh = (hh < 0) ? -hh : ((hh >= Hn) ? (2 * Hn - 2 - hh) : hh);
    const float* xr = xb + (size_t)hh * (Wn * Cn);
#pragma unroll
    for (int dx = 0; dx < 7; dx++) {
      int ww = w + dx - 3;
      ww = (ww < 0) ? -ww : ((ww >= Wn) ? (2 * Wn - 2 - ww) : ww);
      const float4* p = reinterpret_cast<const float4*>(xr + (size_t)ww * Cn);
      float4 v0 = p[0], v1 = p[1], v2 = p[2], v3 = p[3];
      const float* wt = p0w + (dy * 7 + dx) * 16;  // uniform -> SGPR
      conv[0]  += wt[0]  * v0.x; conv[1]  += wt[1]  * v0.y;
      conv[2]  += wt[2]  * v0.z; conv[3]  += wt[3]  * v0.w;
      conv[4]  += wt[4]  * v1.x; conv[5]  += wt[5]  * v1.y;
      conv[6]  += wt[6]  * v1.z; conv[7]  += wt[7]  * v1.w;
      conv[8]  += wt[8]  * v2.x; conv[9]  += wt[9]  * v2.y;
      conv[10] += wt[10] * v2.z; conv[11] += wt[11] * v2.w;
      conv[12] += wt[12] * v3.x; conv[13] += wt[13] * v3.y;
      conv[14] += wt[14] * v3.z; conv[15] += wt[15] * v3.w;
      if (dy == 3 && dx == 3) {
        xc[0] = v0.x;  xc[1] = v0.y;  xc[2] = v0.z;  xc[3] = v0.w;
        xc[4] = v1.x;  xc[5] = v1.y;  xc[6] = v1.z;  xc[7] = v1.w;
        xc[8] = v2.x;  xc[9] = v2.y;  xc[10] = v2.z; xc[11] = v2.w;
        xc[12] = v3.x; xc[13] = v3.y; xc[14] = v3.z; xc[15] = v3.w;
      }
    }
  }
}

// XCD-contiguous row mapping: 2048 blocks -> each of 8 XCDs gets one contiguous
// 256-row chunk (= one batch image) for halo-row L2 reuse.
__device__ inline int swz_row(int bid) { return ((bid & 7) << 8) | (bid >> 3); }

// one-time prep: transpose fc0_w [32][128] -> w0t [128][32] (hid-major)
__global__ __launch_bounds__(256) void nca_prep(const float* __restrict__ fc0w,
                                                float* __restrict__ w0t) {
  int i = blockIdx.x * 256 + threadIdx.x;  // 0..4095
  int hid = i >> 5, k = i & 31;
  w0t[i] = fc0w[k * HIDn + hid];
}

// Stats pass: per (b,h)-row block, build y=[x, conv+b] in LDS, emit per-block
// partials of sum(y_i*y_j) (528) and sum(y_i) (32).
__global__ __launch_bounds__(256) void nca_stats(
    const float* __restrict__ x, const float* __restrict__ p0w,
    const float* __restrict__ p0b, float* __restrict__ partials) {
  __shared__ float sY[256][33];  // +1 pad: conflict-free
  int t = threadIdx.x;
  int row = swz_row(blockIdx.x);
  int b = row >> 8, hr = row & 255;

  const float* xb = x + (size_t)b * (Hn * Wn * Cn);
  float conv[16], xc[16];
  conv_cell(xb, hr, t, p0w, conv, xc);
#pragma unroll
  for (int c = 0; c < 16; c++) {
    sY[t][c] = xc[c];
    sY[t][16 + c] = conv[c] + p0b[c];
  }
  __syncthreads();

  float* outp = partials + (size_t)row * NSTAT;
  for (int e = t; e < NSTAT; e += 256) {
    float acc = 0.0f;
    if (e < NPAIR) {
      int ee = e, i = 0;
      while (ee >= (32 - i)) { ee -= (32 - i); i++; }
      int j = i + ee;
      for (int cell = 0; cell < 256; cell++) acc += sY[cell][i] * sY[cell][j];
    } else {
      int i = e - NPAIR;
      for (int cell = 0; cell < 256; cell++) acc += sY[cell][i];
    }
    outp[e] = acc;
  }
}

// Reduce partials across the 2048 rows (fp64) -> sred[560]
__global__ __launch_bounds__(256) void nca_reduceA(
    const float* __restrict__ partials, double* __restrict__ sred) {
  __shared__ double red[256];
  int e = blockIdx.x;
  int t = threadIdx.x;
  double acc = 0.0;
  for (int row = t; row < NROW; row += 256)
    acc += (double)partials[(size_t)row * NSTAT + e];
  red[t] = acc;
  __syncthreads();
  for (int s2 = 128; s2 > 0; s2 >>= 1) {
    if (t < s2) red[t] += red[t + s2];
    __syncthreads();
  }
  if (t == 0) sred[e] = red[0];
}

// Per-hid BN constants from moments. fc0_b cancels exactly.
__global__ __launch_bounds__(128) void nca_reduceB(
    const double* __restrict__ sred, const float* __restrict__ fc0w,
    const float* __restrict__ gamma, const float* __restrict__ beta,
    float* __restrict__ ss) {
  __shared__ double S[NSTAT];
  int t = threadIdx.x;
  for (int i = t; i < NSTAT; i += 128) S[i] = sred[i];
  __syncthreads();
  double wv[32];
#pragma unroll
  for (int k = 0; k < 32; k++) wv[k] = (double)fc0w[k * HIDn + t];
  double mean_g = 0.0, q = 0.0;
  int e = 0;
  for (int i = 0; i < 32; i++) {
    mean_g += wv[i] * S[NPAIR + i];
    q += wv[i] * wv[i] * S[e]; e++;
    for (int j = i + 1; j < 32; j++) { q += 2.0 * wv[i] * wv[j] * S[e]; e++; }
  }
  const double invN = 1.0 / (double)NCELLS;
  mean_g *= invN; q *= invN;
  double var = q - mean_g * mean_g;
  double scale = (double)gamma[t] / sqrt(var + 1e-5);
  ss[2 * t]     = (float)scale;
  ss[2 * t + 1] = (float)((double)beta[t] - mean_g * scale);
}

// Update pass: conv + fc0 + BN/relu + fc1 + mask. Zero LDS; all weights via
// uniform (scalar) loads from global.
__global__ __launch_bounds__(256) void nca_update(
    const float* __restrict__ x, const float* __restrict__ p0w,
    const float* __restrict__ p0b, const float* __restrict__ w0t,
    const float* __restrict__ fc1w, const float* __restrict__ ssg,
    float* __restrict__ xout, uint32_t fk0, uint32_t fk1) {
  int t = threadIdx.x;
  int row = swz_row(blockIdx.x);
  int b = row >> 8, hr = row & 255;

  const float* xb = x + (size_t)b * (Hn * Wn * Cn);
  float conv[16], y[32];
  conv_cell(xb, hr, t, p0w, conv, y);  // y[0..15] = center x
#pragma unroll
  for (int c = 0; c < 16; c++) y[16 + c] = conv[c] + p0b[c];

  float dx[16];
#pragma unroll
  for (int c = 0; c < 16; c++) dx[c] = 0.0f;

#pragma unroll 2
  for (int hid = 0; hid < HIDn; hid++) {
    const float4* w0 = reinterpret_cast<const float4*>(w0t + (hid << 5));
    float acc = 0.0f;
#pragma unroll
    for (int qd = 0; qd < 8; qd++) {
      float4 wv = w0[qd];  // uniform -> s_load_dwordx16 pairs
      acc += y[4 * qd + 0] * wv.x + y[4 * qd + 1] * wv.y +
             y[4 * qd + 2] * wv.z + y[4 * qd + 3] * wv.w;
    }
    float sc = ssg[2 * hid], sh = ssg[2 * hid + 1];
    float r = fmaxf(acc * sc + sh, 0.0f);
    const float4* w1 = reinterpret_cast<const float4*>(fc1w + (hid << 4));
#pragma unroll
    for (int qd = 0; qd < 4; qd++) {
      float4 wv = w1[qd];
      dx[4 * qd + 0] += r * wv.x; dx[4 * qd + 1] += r * wv.y;
      dx[4 * qd + 2] += r * wv.z; dx[4 * qd + 3] += r * wv.w;
    }
  }

  uint32_t ci = ((uint32_t)row << 8) | (uint32_t)t;
  float m = cell_mask(fk0, fk1, ci);
  float o[16];
  o[0] = y[0];  // INPUT_CHANNELS=1: channel 0 preserved
#pragma unroll
  for (int c = 1; c < 16; c++) o[c] = y[c] + dx[c] * m;
  float4* op = reinterpret_cast<float4*>(xout + (size_t)ci * Cn);
  op[0] = make_float4(o[0], o[1], o[2], o[3]);
  op[1] = make_float4(o[4], o[5], o[6], o[7]);
  op[2] = make_float4(o[8], o[9], o[10], o[11]);
  op[3] = make_float4(o[12], o[13], o[14], o[15]);
}

extern "C" void kernel_launch(void* const* d_in, const int* in_sizes, int n_in,
                              void* d_out, int out_size, void* d_ws, size_t ws_size,
                              hipStream_t stream) {
  (void)in_sizes; (void)n_in; (void)out_size; (void)ws_size;
  const float* x0    = (const float*)d_in[0];
  const float* p0w   = (const float*)d_in[1];
  const float* p0b   = (const float*)d_in[2];
  const float* fc0w  = (const float*)d_in[3];
  // d_in[4] = fc0_b: cancels exactly in BatchNorm -> unused
  const float* gamma = (const float*)d_in[5];
  const float* beta  = (const float*)d_in[6];
  const float* fc1w  = (const float*)d_in[7];
  // d_in[8] = steps (=10, hardcoded)

  // workspace layout
  size_t off = 0;
  float* ws_x = (float*)((char*)d_ws + off); off += (size_t)NCELLS * Cn * 4;        // 33.5 MiB
  float* ws_part = (float*)((char*)d_ws + off); off += (size_t)NROW * NSTAT * 4;    // 4.6 MiB
  double* ws_sred = (double*)((char*)d_ws + off); off += (size_t)NSTAT * 8;
  float* ws_ss = (float*)((char*)d_ws + off); off += (size_t)HIDn * 2 * 4;
  float* ws_w0t = (float*)((char*)d_ws + off);
  float* out = (float*)d_out;

  nca_prep<<<16, 256, 0, stream>>>(fc0w, ws_w0t);

  const float* xin = x0;
  for (int s = 0; s < STEPS; s++) {
    // fold_in(key(42), s): threefry(key=[0,42], count=[0,s])
    uint32_t fk0 = 0u, fk1 = (uint32_t)s;
    tf2x32(0u, 42u, fk0, fk1);
    // ping-pong so the final step lands in d_out
    float* xo = (((STEPS - 1 - s) & 1) != 0) ? ws_x : out;

    nca_stats<<<NROW, 256, 0, stream>>>(xin, p0w, p0b, ws_part);
    nca_reduceA<<<NSTAT, 256, 0, stream>>>(ws_part, ws_sred);
    nca_reduceB<<<1, 128, 0, stream>>>(ws_sred, fc0w, gamma, beta, ws_ss);
    nca_update<<<NROW, 256, 0, stream>>>(xin, p0w, p0b, ws_w0t, fc1w, ws_ss,
                                         xo, fk0, fk1);
    xin = xo;
  }
}

// Round 4
// 2667.786 us; speedup vs baseline: 4.5649x; 4.5649x over previous
//
#include <hip/hip_runtime.h>
#include <stdint.h>

// BasicNCA2D: 10 steps of depthwise7x7(reflect) -> concat -> fc0 -> BN(batch) -> relu -> fc1 -> masked update.
// B=8,H=256,W=256,C=16,HID=128. steps hardcoded to 10.
// RNG: JAX threefry, jax_threefry_partitionable=True: bits[i] = xor(threefry2x32(key,(0,i))).
//
// R3: (a) revert R2's global-uniform weight loads (compiler kept them in VGPRs: 256 VGPR +
// 510MB spill traffic). Weights live in LDS again. (b) nca_stats stores conv+bias to ws;
// nca_update no longer recomputes the conv — pure fc, 2 cells/thread so each LDS weight
// read feeds 2x the FMAs (DS:VALU ratio halved vs R1).

constexpr int Bn = 8;
constexpr int Hn = 256;
constexpr int Wn = 256;
constexpr int Cn = 16;
constexpr int HIDn = 128;
constexpr int NROW = Bn * Hn;              // 2048 (b,h) rows
constexpr int NCELLS = Bn * Hn * Wn;       // 524288
constexpr int NPAIR = 528;                 // 32*33/2 unique second moments of y
constexpr int NSTAT = 560;                 // pairs + 32 first moments
constexpr int STEPS = 10;

__host__ __device__ inline uint32_t rotl32(uint32_t v, int r) {
  return (v << r) | (v >> (32 - r));
}

// Threefry-2x32, 20 rounds, exactly as jax/_src/prng.py
__host__ __device__ inline void tf2x32(uint32_t k0, uint32_t k1,
                                       uint32_t& x0, uint32_t& x1) {
  uint32_t k2 = k0 ^ k1 ^ 0x1BD11BDAu;
  x0 += k0; x1 += k1;
  x0 += x1; x1 = rotl32(x1, 13); x1 ^= x0;
  x0 += x1; x1 = rotl32(x1, 15); x1 ^= x0;
  x0 += x1; x1 = rotl32(x1, 26); x1 ^= x0;
  x0 += x1; x1 = rotl32(x1,  6); x1 ^= x0;
  x0 += k1; x1 += k2 + 1u;
  x0 += x1; x1 = rotl32(x1, 17); x1 ^= x0;
  x0 += x1; x1 = rotl32(x1, 29); x1 ^= x0;
  x0 += x1; x1 = rotl32(x1, 16); x1 ^= x0;
  x0 += x1; x1 = rotl32(x1, 24); x1 ^= x0;
  x0 += k2; x1 += k0 + 2u;
  x0 += x1; x1 = rotl32(x1, 13); x1 ^= x0;
  x0 += x1; x1 = rotl32(x1, 15); x1 ^= x0;
  x0 += x1; x1 = rotl32(x1, 26); x1 ^= x0;
  x0 += x1; x1 = rotl32(x1,  6); x1 ^= x0;
  x0 += k0; x1 += k1 + 3u;
  x0 += x1; x1 = rotl32(x1, 17); x1 ^= x0;
  x0 += x1; x1 = rotl32(x1, 29); x1 ^= x0;
  x0 += x1; x1 = rotl32(x1, 16); x1 ^= x0;
  x0 += x1; x1 = rotl32(x1, 24); x1 ^= x0;
  x0 += k1; x1 += k2 + 4u;
  x0 += x1; x1 = rotl32(x1, 13); x1 ^= x0;
  x0 += x1; x1 = rotl32(x1, 15); x1 ^= x0;
  x0 += x1; x1 = rotl32(x1, 26); x1 ^= x0;
  x0 += x1; x1 = rotl32(x1,  6); x1 ^= x0;
  x0 += k2; x1 += k0 + 5u;
}

__device__ inline float cell_mask(uint32_t fk0, uint32_t fk1, uint32_t ci) {
  uint32_t a = 0u, b2 = ci;
  tf2x32(fk0, fk1, a, b2);
  uint32_t bits = a ^ b2;
  float u = __uint_as_float((bits >> 9) | 0x3f800000u) - 1.0f;
  return (u > 0.5f) ? 1.0f : 0.0f;
}

// depthwise 7x7 reflect conv for one cell; weights from LDS (broadcast reads).
__device__ inline void conv_cell(const float* __restrict__ xb, int hr, int w,
                                 const float* __restrict__ sW,
                                 float conv[16], float xc[16]) {
#pragma unroll
  for (int c = 0; c < 16; c++) conv[c] = 0.0f;
  for (int dy = 0; dy < 7; dy++) {
    int hh = hr + dy - 3;
    hh = (hh < 0) ? -hh : ((hh >= Hn) ? (2 * Hn - 2 - hh) : hh);
    const float* xr = xb + (size_t)hh * (Wn * Cn);
#pragma unroll
    for (int dx = 0; dx < 7; dx++) {
      int ww = w + dx - 3;
      ww = (ww < 0) ? -ww : ((ww >= Wn) ? (2 * Wn - 2 - ww) : ww);
      const float4* p = reinterpret_cast<const float4*>(xr + (size_t)ww * Cn);
      float4 v0 = p[0], v1 = p[1], v2 = p[2], v3 = p[3];
      const float* wt = sW + (dy * 7 + dx) * 16;
      conv[0]  += wt[0]  * v0.x; conv[1]  += wt[1]  * v0.y;
      conv[2]  += wt[2]  * v0.z; conv[3]  += wt[3]  * v0.w;
      conv[4]  += wt[4]  * v1.x; conv[5]  += wt[5]  * v1.y;
      conv[6]  += wt[6]  * v1.z; conv[7]  += wt[7]  * v1.w;
      conv[8]  += wt[8]  * v2.x; conv[9]  += wt[9]  * v2.y;
      conv[10] += wt[10] * v2.z; conv[11] += wt[11] * v2.w;
      conv[12] += wt[12] * v3.x; conv[13] += wt[13] * v3.y;
      conv[14] += wt[14] * v3.z; conv[15] += wt[15] * v3.w;
      if (dy == 3 && dx == 3) {
        xc[0] = v0.x;  xc[1] = v0.y;  xc[2] = v0.z;  xc[3] = v0.w;
        xc[4] = v1.x;  xc[5] = v1.y;  xc[6] = v1.z;  xc[7] = v1.w;
        xc[8] = v2.x;  xc[9] = v2.y;  xc[10] = v2.z; xc[11] = v2.w;
        xc[12] = v3.x; xc[13] = v3.y; xc[14] = v3.z; xc[15] = v3.w;
      }
    }
  }
}

// XCD-contiguous row mapping for the conv pass (halo-row L2 reuse).
__device__ inline int swz_row(int bid) { return ((bid & 7) << 8) | (bid >> 3); }

// one-time prep: transpose fc0_w [32][128] -> w0t [128][32] (hid-major)
__global__ __launch_bounds__(256) void nca_prep(const float* __restrict__ fc0w,
                                                float* __restrict__ w0t) {
  int i = blockIdx.x * 256 + threadIdx.x;  // 0..4095
  int hid = i >> 5, k = i & 31;
  w0t[i] = fc0w[k * HIDn + hid];
}

// Stats pass: conv once per cell; store conv+bias to ws_yc; emit gram partials.
__global__ __launch_bounds__(256) void nca_stats(
    const float* __restrict__ x, const float* __restrict__ p0w,
    const float* __restrict__ p0b, float* __restrict__ partials,
    float* __restrict__ yc) {
  __shared__ float sY[256][33];  // +1 pad: conflict-free
  __shared__ float sW[784];
  __shared__ float sB[16];
  int t = threadIdx.x;
  int row = swz_row(blockIdx.x);
  int b = row >> 8, hr = row & 255;
  for (int i = t; i < 784; i += 256) sW[i] = p0w[i];
  if (t < 16) sB[t] = p0b[t];
  __syncthreads();

  const float* xb = x + (size_t)b * (Hn * Wn * Cn);
  float conv[16], xc[16];
  conv_cell(xb, hr, t, sW, conv, xc);
#pragma unroll
  for (int c = 0; c < 16; c++) {
    sY[t][c] = xc[c];
    sY[t][16 + c] = conv[c] + sB[c];
  }
  // store conv+bias for the update pass (update will not redo the conv)
  size_t ci = (size_t)row * 256 + t;
  float4* yp = reinterpret_cast<float4*>(yc + ci * Cn);
  yp[0] = make_float4(conv[0] + sB[0], conv[1] + sB[1], conv[2] + sB[2], conv[3] + sB[3]);
  yp[1] = make_float4(conv[4] + sB[4], conv[5] + sB[5], conv[6] + sB[6], conv[7] + sB[7]);
  yp[2] = make_float4(conv[8] + sB[8], conv[9] + sB[9], conv[10] + sB[10], conv[11] + sB[11]);
  yp[3] = make_float4(conv[12] + sB[12], conv[13] + sB[13], conv[14] + sB[14], conv[15] + sB[15]);
  __syncthreads();

  float* outp = partials + (size_t)row * NSTAT;
  for (int e = t; e < NSTAT; e += 256) {
    float acc = 0.0f;
    if (e < NPAIR) {
      int ee = e, i = 0;
      while (ee >= (32 - i)) { ee -= (32 - i); i++; }
      int j = i + ee;
      for (int cell = 0; cell < 256; cell++) acc += sY[cell][i] * sY[cell][j];
    } else {
      int i = e - NPAIR;
      for (int cell = 0; cell < 256; cell++) acc += sY[cell][i];
    }
    outp[e] = acc;
  }
}

// Reduce partials across the 2048 rows (fp64) -> sred[560]
__global__ __launch_bounds__(256) void nca_reduceA(
    const float* __restrict__ partials, double* __restrict__ sred) {
  __shared__ double red[256];
  int e = blockIdx.x;
  int t = threadIdx.x;
  double acc = 0.0;
  for (int row = t; row < NROW; row += 256)
    acc += (double)partials[(size_t)row * NSTAT + e];
  red[t] = acc;
  __syncthreads();
  for (int s2 = 128; s2 > 0; s2 >>= 1) {
    if (t < s2) red[t] += red[t + s2];
    __syncthreads();
  }
  if (t == 0) sred[e] = red[0];
}

// Per-hid BN constants from moments. fc0_b cancels exactly.
__global__ __launch_bounds__(128) void nca_reduceB(
    const double* __restrict__ sred, const float* __restrict__ fc0w,
    const float* __restrict__ gamma, const float* __restrict__ beta,
    float* __restrict__ ss) {
  __shared__ double S[NSTAT];
  int t = threadIdx.x;
  for (int i = t; i < NSTAT; i += 128) S[i] = sred[i];
  __syncthreads();
  double wv[32];
#pragma unroll
  for (int k = 0; k < 32; k++) wv[k] = (double)fc0w[k * HIDn + t];
  double mean_g = 0.0, q = 0.0;
  int e = 0;
  for (int i = 0; i < 32; i++) {
    mean_g += wv[i] * S[NPAIR + i];
    q += wv[i] * wv[i] * S[e]; e++;
    for (int j = i + 1; j < 32; j++) { q += 2.0 * wv[i] * wv[j] * S[e]; e++; }
  }
  const double invN = 1.0 / (double)NCELLS;
  mean_g *= invN; q *= invN;
  double var = q - mean_g * mean_g;
  double scale = (double)gamma[t] / sqrt(var + 1e-5);
  ss[2 * t]     = (float)scale;
  ss[2 * t + 1] = (float)((double)beta[t] - mean_g * scale);
}

// Update pass: pure fc (conv read from ws_yc). 2 cells/thread; weights in LDS.
__global__ __launch_bounds__(512) void nca_update(
    const float* __restrict__ x, const float* __restrict__ yc,
    const float* __restrict__ w0t, const float* __restrict__ fc1w,
    const float* __restrict__ ssg, float* __restrict__ xout,
    uint32_t fk0, uint32_t fk1) {
  __shared__ float sW0[HIDn * 32];  // 16KB, hid-major
  __shared__ float sW1[HIDn * 16];  // 8KB, hid-major
  __shared__ float2 sSS[HIDn];      // 1KB
  int t = threadIdx.x;
  for (int i = t; i < HIDn * 32; i += 512) sW0[i] = w0t[i];
  for (int i = t; i < HIDn * 16; i += 512) sW1[i] = fc1w[i];
  if (t < HIDn) sSS[t] = reinterpret_cast<const float2*>(ssg)[t];
  __syncthreads();

  uint32_t ci0 = (uint32_t)blockIdx.x * 1024u + (uint32_t)t;
  uint32_t ci1 = ci0 + 512u;

  float ya[32], yb[32];
  {
    const float4* xa = reinterpret_cast<const float4*>(x + (size_t)ci0 * Cn);
    const float4* ca = reinterpret_cast<const float4*>(yc + (size_t)ci0 * Cn);
    const float4* xb4 = reinterpret_cast<const float4*>(x + (size_t)ci1 * Cn);
    const float4* cb = reinterpret_cast<const float4*>(yc + (size_t)ci1 * Cn);
#pragma unroll
    for (int q = 0; q < 4; q++) {
      float4 v = xa[q];
      ya[4 * q + 0] = v.x; ya[4 * q + 1] = v.y; ya[4 * q + 2] = v.z; ya[4 * q + 3] = v.w;
      float4 c = ca[q];
      ya[16 + 4 * q + 0] = c.x; ya[16 + 4 * q + 1] = c.y; ya[16 + 4 * q + 2] = c.z; ya[16 + 4 * q + 3] = c.w;
      float4 v2 = xb4[q];
      yb[4 * q + 0] = v2.x; yb[4 * q + 1] = v2.y; yb[4 * q + 2] = v2.z; yb[4 * q + 3] = v2.w;
      float4 c2 = cb[q];
      yb[16 + 4 * q + 0] = c2.x; yb[16 + 4 * q + 1] = c2.y; yb[16 + 4 * q + 2] = c2.z; yb[16 + 4 * q + 3] = c2.w;
    }
  }

  float dxa[16], dxb[16];
#pragma unroll
  for (int c = 0; c < 16; c++) { dxa[c] = 0.0f; dxb[c] = 0.0f; }

#pragma unroll 2
  for (int hid = 0; hid < HIDn; hid++) {
    const float4* w0 = reinterpret_cast<const float4*>(sW0 + (hid << 5));
    float pa0 = 0.0f, pa1 = 0.0f, pb0 = 0.0f, pb1 = 0.0f;
#pragma unroll
    for (int q = 0; q < 8; q += 2) {
      float4 u = w0[q], v = w0[q + 1];
      pa0 += ya[4 * q + 0] * u.x + ya[4 * q + 1] * u.y + ya[4 * q + 2] * u.z + ya[4 * q + 3] * u.w;
      pb0 += yb[4 * q + 0] * u.x + yb[4 * q + 1] * u.y + yb[4 * q + 2] * u.z + yb[4 * q + 3] * u.w;
      pa1 += ya[4 * q + 4] * v.x + ya[4 * q + 5] * v.y + ya[4 * q + 6] * v.z + ya[4 * q + 7] * v.w;
      pb1 += yb[4 * q + 4] * v.x + yb[4 * q + 5] * v.y + yb[4 * q + 6] * v.z + yb[4 * q + 7] * v.w;
    }
    float2 ssv = sSS[hid];
    float ra = fmaxf((pa0 + pa1) * ssv.x + ssv.y, 0.0f);
    float rb = fmaxf((pb0 + pb1) * ssv.x + ssv.y, 0.0f);
    const float4* w1 = reinterpret_cast<const float4*>(sW1 + (hid << 4));
#pragma unroll
    for (int q = 0; q < 4; q++) {
      float4 w = w1[q];
      dxa[4 * q + 0] += ra * w.x; dxa[4 * q + 1] += ra * w.y;
      dxa[4 * q + 2] += ra * w.z; dxa[4 * q + 3] += ra * w.w;
      dxb[4 * q + 0] += rb * w.x; dxb[4 * q + 1] += rb * w.y;
      dxb[4 * q + 2] += rb * w.z; dxb[4 * q + 3] += rb * w.w;
    }
  }

  float ma = cell_mask(fk0, fk1, ci0);
  float mb = cell_mask(fk0, fk1, ci1);
  float4* oa = reinterpret_cast<float4*>(xout + (size_t)ci0 * Cn);
  float4* ob = reinterpret_cast<float4*>(xout + (size_t)ci1 * Cn);
  float o[16];
  o[0] = ya[0];
#pragma unroll
  for (int c = 1; c < 16; c++) o[c] = ya[c] + dxa[c] * ma;
  oa[0] = make_float4(o[0], o[1], o[2], o[3]);
  oa[1] = make_float4(o[4], o[5], o[6], o[7]);
  oa[2] = make_float4(o[8], o[9], o[10], o[11]);
  oa[3] = make_float4(o[12], o[13], o[14], o[15]);
  o[0] = yb[0];
#pragma unroll
  for (int c = 1; c < 16; c++) o[c] = yb[c] + dxb[c] * mb;
  ob[0] = make_float4(o[0], o[1], o[2], o[3]);
  ob[1] = make_float4(o[4], o[5], o[6], o[7]);
  ob[2] = make_float4(o[8], o[9], o[10], o[11]);
  ob[3] = make_float4(o[12], o[13], o[14], o[15]);
}

extern "C" void kernel_launch(void* const* d_in, const int* in_sizes, int n_in,
                              void* d_out, int out_size, void* d_ws, size_t ws_size,
                              hipStream_t stream) {
  (void)in_sizes; (void)n_in; (void)out_size; (void)ws_size;
  const float* x0    = (const float*)d_in[0];
  const float* p0w   = (const float*)d_in[1];
  const float* p0b   = (const float*)d_in[2];
  const float* fc0w  = (const float*)d_in[3];
  // d_in[4] = fc0_b: cancels exactly in BatchNorm -> unused
  const float* gamma = (const float*)d_in[5];
  const float* beta  = (const float*)d_in[6];
  const float* fc1w  = (const float*)d_in[7];
  // d_in[8] = steps (=10, hardcoded)

  // workspace layout (~72 MB)
  size_t off = 0;
  float* ws_x = (float*)((char*)d_ws + off); off += (size_t)NCELLS * Cn * 4;        // 33.5 MiB
  float* ws_yc = (float*)((char*)d_ws + off); off += (size_t)NCELLS * Cn * 4;       // 33.5 MiB
  float* ws_part = (float*)((char*)d_ws + off); off += (size_t)NROW * NSTAT * 4;    // 4.6 MiB
  double* ws_sred = (double*)((char*)d_ws + off); off += (size_t)NSTAT * 8;
  float* ws_ss = (float*)((char*)d_ws + off); off += (size_t)HIDn * 2 * 4;
  float* ws_w0t = (float*)((char*)d_ws + off);
  float* out = (float*)d_out;

  nca_prep<<<16, 256, 0, stream>>>(fc0w, ws_w0t);

  const float* xin = x0;
  for (int s = 0; s < STEPS; s++) {
    uint32_t fk0 = 0u, fk1 = (uint32_t)s;
    tf2x32(0u, 42u, fk0, fk1);
    float* xo = (((STEPS - 1 - s) & 1) != 0) ? ws_x : out;

    nca_stats<<<NROW, 256, 0, stream>>>(xin, p0w, p0b, ws_part, ws_yc);
    nca_reduceA<<<NSTAT, 256, 0, stream>>>(ws_part, ws_sred);
    nca_reduceB<<<1, 128, 0, stream>>>(ws_sred, fc0w, gamma, beta, ws_ss);
    nca_update<<<NCELLS / 1024, 512, 0, stream>>>(xin, ws_yc, ws_w0t, fc1w, ws_ss,
                                                  xo, fk0, fk1);
    xin = xo;
  }
}

// Round 5
// 1537.139 us; speedup vs baseline: 7.9227x; 1.7356x over previous
//
#include <hip/hip_runtime.h>
#include <stdint.h>

// BasicNCA2D: 10 steps of depthwise7x7(reflect) -> concat -> fc0 -> BN(batch) -> relu -> fc1 -> masked update.
// B=8,H=256,W=256,C=16,HID=128. steps hardcoded to 10.
// RNG: JAX threefry, jax_threefry_partitionable=True: bits[i] = xor(threefry2x32(key,(0,i))).
//
// R4: nca_update rewritten on MFMA (bf16). stats emits y=[x|conv+b] as bf16[cell][32];
// update does fc0 as 8x mfma_16x16x32_bf16 (K=32 one shot, A-frags coalesced straight
// from global), BN+relu on f32 accs, bf16 repack via per-wave 4KB LDS (XOR-swizzled,
// k-permuted identically on A and B so the permutation cancels), fc1 as 4 MFMAs (K=128).
// BN statistics remain fp32/fp64 (reference-exact); only the fc data path is bf16.

constexpr int Bn = 8;
constexpr int Hn = 256;
constexpr int Wn = 256;
constexpr int Cn = 16;
constexpr int HIDn = 128;
constexpr int NROW = Bn * Hn;              // 2048 (b,h) rows
constexpr int NCELLS = Bn * Hn * Wn;       // 524288
constexpr int NPAIR = 528;                 // 32*33/2 unique second moments of y
constexpr int NSTAT = 560;                 // pairs + 32 first moments
constexpr int STEPS = 10;

typedef __attribute__((ext_vector_type(8))) short bf16x8;
typedef __attribute__((ext_vector_type(4))) float f32x4;

__host__ __device__ inline uint32_t rotl32(uint32_t v, int r) {
  return (v << r) | (v >> (32 - r));
}

// Threefry-2x32, 20 rounds, exactly as jax/_src/prng.py
__host__ __device__ inline void tf2x32(uint32_t k0, uint32_t k1,
                                       uint32_t& x0, uint32_t& x1) {
  uint32_t k2 = k0 ^ k1 ^ 0x1BD11BDAu;
  x0 += k0; x1 += k1;
  x0 += x1; x1 = rotl32(x1, 13); x1 ^= x0;
  x0 += x1; x1 = rotl32(x1, 15); x1 ^= x0;
  x0 += x1; x1 = rotl32(x1, 26); x1 ^= x0;
  x0 += x1; x1 = rotl32(x1,  6); x1 ^= x0;
  x0 += k1; x1 += k2 + 1u;
  x0 += x1; x1 = rotl32(x1, 17); x1 ^= x0;
  x0 += x1; x1 = rotl32(x1, 29); x1 ^= x0;
  x0 += x1; x1 = rotl32(x1, 16); x1 ^= x0;
  x0 += x1; x1 = rotl32(x1, 24); x1 ^= x0;
  x0 += k2; x1 += k0 + 2u;
  x0 += x1; x1 = rotl32(x1, 13); x1 ^= x0;
  x0 += x1; x1 = rotl32(x1, 15); x1 ^= x0;
  x0 += x1; x1 = rotl32(x1, 26); x1 ^= x0;
  x0 += x1; x1 = rotl32(x1,  6); x1 ^= x0;
  x0 += k0; x1 += k1 + 3u;
  x0 += x1; x1 = rotl32(x1, 17); x1 ^= x0;
  x0 += x1; x1 = rotl32(x1, 29); x1 ^= x0;
  x0 += x1; x1 = rotl32(x1, 16); x1 ^= x0;
  x0 += x1; x1 = rotl32(x1, 24); x1 ^= x0;
  x0 += k1; x1 += k2 + 4u;
  x0 += x1; x1 = rotl32(x1, 13); x1 ^= x0;
  x0 += x1; x1 = rotl32(x1, 15); x1 ^= x0;
  x0 += x1; x1 = rotl32(x1, 26); x1 ^= x0;
  x0 += x1; x1 = rotl32(x1,  6); x1 ^= x0;
  x0 += k2; x1 += k0 + 5u;
}

__device__ inline float cell_mask(uint32_t fk0, uint32_t fk1, uint32_t ci) {
  uint32_t a = 0u, b2 = ci;
  tf2x32(fk0, fk1, a, b2);
  uint32_t bits = a ^ b2;
  float u = __uint_as_float((bits >> 9) | 0x3f800000u) - 1.0f;
  return (u > 0.5f) ? 1.0f : 0.0f;
}

// fp32 -> bf16 bits, round-to-nearest-even
__device__ inline uint32_t f2bf(float f) {
  uint32_t u = __float_as_uint(f);
  return (u + 0x7fffu + ((u >> 16) & 1u)) >> 16;
}

// depthwise 7x7 reflect conv for one cell; weights from LDS (broadcast reads).
__device__ inline void conv_cell(const float* __restrict__ xb, int hr, int w,
                                 const float* __restrict__ sW,
                                 float conv[16], float xc[16]) {
#pragma unroll
  for (int c = 0; c < 16; c++) conv[c] = 0.0f;
  for (int dy = 0; dy < 7; dy++) {
    int hh = hr + dy - 3;
    hh = (hh < 0) ? -hh : ((hh >= Hn) ? (2 * Hn - 2 - hh) : hh);
    const float* xr = xb + (size_t)hh * (Wn * Cn);
#pragma unroll
    for (int dx = 0; dx < 7; dx++) {
      int ww = w + dx - 3;
      ww = (ww < 0) ? -ww : ((ww >= Wn) ? (2 * Wn - 2 - ww) : ww);
      const float4* p = reinterpret_cast<const float4*>(xr + (size_t)ww * Cn);
      float4 v0 = p[0], v1 = p[1], v2 = p[2], v3 = p[3];
      const float* wt = sW + (dy * 7 + dx) * 16;
      conv[0]  += wt[0]  * v0.x; conv[1]  += wt[1]  * v0.y;
      conv[2]  += wt[2]  * v0.z; conv[3]  += wt[3]  * v0.w;
      conv[4]  += wt[4]  * v1.x; conv[5]  += wt[5]  * v1.y;
      conv[6]  += wt[6]  * v1.z; conv[7]  += wt[7]  * v1.w;
      conv[8]  += wt[8]  * v2.x; conv[9]  += wt[9]  * v2.y;
      conv[10] += wt[10] * v2.z; conv[11] += wt[11] * v2.w;
      conv[12] += wt[12] * v3.x; conv[13] += wt[13] * v3.y;
      conv[14] += wt[14] * v3.z; conv[15] += wt[15] * v3.w;
      if (dy == 3 && dx == 3) {
        xc[0] = v0.x;  xc[1] = v0.y;  xc[2] = v0.z;  xc[3] = v0.w;
        xc[4] = v1.x;  xc[5] = v1.y;  xc[6] = v1.z;  xc[7] = v1.w;
        xc[8] = v2.x;  xc[9] = v2.y;  xc[10] = v2.z; xc[11] = v2.w;
        xc[12] = v3.x; xc[13] = v3.y; xc[14] = v3.z; xc[15] = v3.w;
      }
    }
  }
}

// XCD-contiguous row mapping for the conv pass (halo-row L2 reuse).
__device__ inline int swz_row(int bid) { return ((bid & 7) << 8) | (bid >> 3); }

// one-time prep:
//  w0bf [n=128][k=32] bf16 : w0bf[n*32+k] = bf16(fc0w[k*128+n])
//  w1p  [c=16][kl=128] bf16: n = (kl&7)*16 + (kl>>3); w1p[c*128+kl] = bf16(fc1w[n*16+c])
__global__ __launch_bounds__(256) void nca_prep(const float* __restrict__ fc0w,
                                                const float* __restrict__ fc1w,
                                                uint16_t* __restrict__ w0bf,
                                                uint16_t* __restrict__ w1p) {
  int i = blockIdx.x * 256 + threadIdx.x;  // 0..6143
  if (i < 4096) {
    int n = i >> 5, k = i & 31;
    w0bf[i] = (uint16_t)f2bf(fc0w[k * HIDn + n]);
  } else {
    int j = i - 4096;
    int c = j >> 7, kl = j & 127;
    int n = (kl & 7) * 16 + (kl >> 3);
    w1p[j] = (uint16_t)f2bf(fc1w[n * 16 + c]);
  }
}

// Stats pass: conv once per cell; store y=[x|conv+b] bf16 to ws_ybf; emit gram partials.
__global__ __launch_bounds__(256) void nca_stats(
    const float* __restrict__ x, const float* __restrict__ p0w,
    const float* __restrict__ p0b, float* __restrict__ partials,
    uint16_t* __restrict__ ybf) {
  __shared__ float sY[256][33];  // +1 pad: conflict-free
  __shared__ float sW[784];
  __shared__ float sB[16];
  int t = threadIdx.x;
  int row = swz_row(blockIdx.x);
  int b = row >> 8, hr = row & 255;
  for (int i = t; i < 784; i += 256) sW[i] = p0w[i];
  if (t < 16) sB[t] = p0b[t];
  __syncthreads();

  const float* xb = x + (size_t)b * (Hn * Wn * Cn);
  float conv[16], xc[16];
  conv_cell(xb, hr, t, sW, conv, xc);
  float yv[32];
#pragma unroll
  for (int c = 0; c < 16; c++) {
    yv[c] = xc[c];
    yv[16 + c] = conv[c] + sB[c];
    sY[t][c] = xc[c];
    sY[t][16 + c] = yv[16 + c];
  }
  // bf16 y for the MFMA update pass
  size_t ci = (size_t)row * 256 + t;
  uint32_t pk[16];
#pragma unroll
  for (int q = 0; q < 16; q++)
    pk[q] = f2bf(yv[2 * q]) | (f2bf(yv[2 * q + 1]) << 16);
  uint4* yp = reinterpret_cast<uint4*>(ybf + ci * 32);
  yp[0] = make_uint4(pk[0], pk[1], pk[2], pk[3]);
  yp[1] = make_uint4(pk[4], pk[5], pk[6], pk[7]);
  yp[2] = make_uint4(pk[8], pk[9], pk[10], pk[11]);
  yp[3] = make_uint4(pk[12], pk[13], pk[14], pk[15]);
  __syncthreads();

  float* outp = partials + (size_t)row * NSTAT;
  for (int e = t; e < NSTAT; e += 256) {
    float acc = 0.0f;
    if (e < NPAIR) {
      int ee = e, i = 0;
      while (ee >= (32 - i)) { ee -= (32 - i); i++; }
      int j = i + ee;
      for (int cell = 0; cell < 256; cell++) acc += sY[cell][i] * sY[cell][j];
    } else {
      int i = e - NPAIR;
      for (int cell = 0; cell < 256; cell++) acc += sY[cell][i];
    }
    outp[e] = acc;
  }
}

// Reduce partials across the 2048 rows (fp64) -> sred[560]
__global__ __launch_bounds__(256) void nca_reduceA(
    const float* __restrict__ partials, double* __restrict__ sred) {
  __shared__ double red[256];
  int e = blockIdx.x;
  int t = threadIdx.x;
  double acc = 0.0;
  for (int row = t; row < NROW; row += 256)
    acc += (double)partials[(size_t)row * NSTAT + e];
  red[t] = acc;
  __syncthreads();
  for (int s2 = 128; s2 > 0; s2 >>= 1) {
    if (t < s2) red[t] += red[t + s2];
    __syncthreads();
  }
  if (t == 0) sred[e] = red[0];
}

// Per-hid BN constants from moments. fc0_b cancels exactly.
__global__ __launch_bounds__(128) void nca_reduceB(
    const double* __restrict__ sred, const float* __restrict__ fc0w,
    const float* __restrict__ gamma, const float* __restrict__ beta,
    float* __restrict__ ss) {
  __shared__ double S[NSTAT];
  int t = threadIdx.x;
  for (int i = t; i < NSTAT; i += 128) S[i] = sred[i];
  __syncthreads();
  double wv[32];
#pragma unroll
  for (int k = 0; k < 32; k++) wv[k] = (double)fc0w[k * HIDn + t];
  double mean_g = 0.0, q = 0.0;
  int e = 0;
  for (int i = 0; i < 32; i++) {
    mean_g += wv[i] * S[NPAIR + i];
    q += wv[i] * wv[i] * S[e]; e++;
    for (int j = i + 1; j < 32; j++) { q += 2.0 * wv[i] * wv[j] * S[e]; e++; }
  }
  const double invN = 1.0 / (double)NCELLS;
  mean_g *= invN; q *= invN;
  double var = q - mean_g * mean_g;
  double scale = (double)gamma[t] / sqrt(var + 1e-5);
  ss[2 * t]     = (float)scale;
  ss[2 * t + 1] = (float)((double)beta[t] - mean_g * scale);
}

// MFMA update: per wave, 16-cell M-tiles. fc0: 8x mfma_16x16x32_bf16 (K=32);
// BN+relu on f32 accs; repack bf16 via per-wave LDS (XOR swizzle, k-permuted);
// fc1: 4x mfma_16x16x32_bf16 (K=128); residual+mask epilogue.
__global__ __launch_bounds__(256) void nca_update_mfma(
    const float* __restrict__ x, const uint16_t* __restrict__ ybf,
    const uint16_t* __restrict__ w0bf, const uint16_t* __restrict__ w1p,
    const float* __restrict__ ssg, float* __restrict__ xout,
    uint32_t fk0, uint32_t fk1) {
  __shared__ short hbuf[4][16 * 128];  // 4KB per wave
  int t = threadIdx.x;
  int lane = t & 63, wid = t >> 6;
  int col = lane & 15, g = lane >> 4;
  short* hb = hbuf[wid];

  // hoisted operand fragments (tile-invariant)
  bf16x8 b0[8];
#pragma unroll
  for (int nt = 0; nt < 8; nt++) {
    int n = nt * 16 + col;
    b0[nt] = *reinterpret_cast<const bf16x8*>(w0bf + n * 32 + g * 8);
  }
  bf16x8 b2[4];
#pragma unroll
  for (int kk = 0; kk < 4; kk++)
    b2[kk] = *reinterpret_cast<const bf16x8*>(w1p + col * 128 + kk * 32 + g * 8);
  float sc[8], sh[8];
#pragma unroll
  for (int nt = 0; nt < 8; nt++) {
    float2 v = reinterpret_cast<const float2*>(ssg)[nt * 16 + col];
    sc[nt] = v.x; sh[nt] = v.y;
  }

  uint32_t waveBase = (uint32_t)blockIdx.x * 1024u + (uint32_t)wid * 256u;
  for (int grp = 0; grp < 4; grp++) {
    uint32_t grpBase = waveBase + (uint32_t)grp * 64u;
    float mval = cell_mask(fk0, fk1, grpBase + (uint32_t)lane);
#pragma unroll 1
    for (int tt = 0; tt < 4; tt++) {
      uint32_t tb = grpBase + (uint32_t)tt * 16u;
      // A0 frag: wave reads contiguous 1KB from ybf
      bf16x8 a0 = *reinterpret_cast<const bf16x8*>(
          ybf + (size_t)(tb + col) * 32 + g * 8);
      // residual x prefetch
      float xv[4];
#pragma unroll
      for (int r = 0; r < 4; r++)
        xv[r] = x[(size_t)(tb + g * 4 + r) * Cn + col];
      // fc0
      f32x4 h[8];
#pragma unroll
      for (int nt = 0; nt < 8; nt++) {
        f32x4 z = {0.f, 0.f, 0.f, 0.f};
        h[nt] = __builtin_amdgcn_mfma_f32_16x16x32_bf16(a0, b0[nt], z, 0, 0, 0);
      }
      // BN + relu + bf16 pack -> LDS [m][k_lds], k_lds = col16*8 + nt, XOR swizzle
#pragma unroll
      for (int r = 0; r < 4; r++) {
        int m = g * 4 + r;
        uint32_t u[4];
#pragma unroll
        for (int q = 0; q < 4; q++) {
          float v0 = fmaxf(h[2 * q][r] * sc[2 * q] + sh[2 * q], 0.0f);
          float v1 = fmaxf(h[2 * q + 1][r] * sc[2 * q + 1] + sh[2 * q + 1], 0.0f);
          u[q] = f2bf(v0) | (f2bf(v1) << 16);
        }
        int idx = m * 128 + ((col * 8) ^ ((m & 7) << 3));
        *reinterpret_cast<uint4*>(hb + idx) = make_uint4(u[0], u[1], u[2], u[3]);
      }
      // fc1 over k_lds (w1p permuted identically -> permutation cancels)
      f32x4 dx = {0.f, 0.f, 0.f, 0.f};
#pragma unroll
      for (int kk = 0; kk < 4; kk++) {
        int idx = col * 128 + (((kk * 32) + g * 8) ^ ((col & 7) << 3));
        bf16x8 a2 = *reinterpret_cast<const bf16x8*>(hb + idx);
        dx = __builtin_amdgcn_mfma_f32_16x16x32_bf16(a2, b2[kk], dx, 0, 0, 0);
      }
      // epilogue: o = x + mask*dx (channel 0 preserved)
#pragma unroll
      for (int r = 0; r < 4; r++) {
        int m = g * 4 + r;
        float mk = __shfl(mval, tt * 16 + m);
        float o = xv[r] + dx[r] * mk;
        if (col == 0) o = xv[r];
        xout[(size_t)(tb + m) * Cn + col] = o;
      }
    }
  }
}

extern "C" void kernel_launch(void* const* d_in, const int* in_sizes, int n_in,
                              void* d_out, int out_size, void* d_ws, size_t ws_size,
                              hipStream_t stream) {
  (void)in_sizes; (void)n_in; (void)out_size; (void)ws_size;
  const float* x0    = (const float*)d_in[0];
  const float* p0w   = (const float*)d_in[1];
  const float* p0b   = (const float*)d_in[2];
  const float* fc0w  = (const float*)d_in[3];
  // d_in[4] = fc0_b: cancels exactly in BatchNorm -> unused
  const float* gamma = (const float*)d_in[5];
  const float* beta  = (const float*)d_in[6];
  const float* fc1w  = (const float*)d_in[7];
  // d_in[8] = steps (=10, hardcoded)

  // workspace layout (~72 MB)
  size_t off = 0;
  float* ws_x = (float*)((char*)d_ws + off); off += (size_t)NCELLS * Cn * 4;        // 33.5 MiB
  uint16_t* ws_ybf = (uint16_t*)((char*)d_ws + off); off += (size_t)NCELLS * 32 * 2; // 33.5 MiB
  float* ws_part = (float*)((char*)d_ws + off); off += (size_t)NROW * NSTAT * 4;    // 4.6 MiB
  double* ws_sred = (double*)((char*)d_ws + off); off += (size_t)NSTAT * 8;
  float* ws_ss = (float*)((char*)d_ws + off); off += (size_t)HIDn * 2 * 4;
  uint16_t* ws_w0bf = (uint16_t*)((char*)d_ws + off); off += 4096 * 2;
  uint16_t* ws_w1p = (uint16_t*)((char*)d_ws + off); off += 2048 * 2;
  float* out = (float*)d_out;

  nca_prep<<<24, 256, 0, stream>>>(fc0w, fc1w, ws_w0bf, ws_w1p);

  const float* xin = x0;
  for (int s = 0; s < STEPS; s++) {
    uint32_t fk0 = 0u, fk1 = (uint32_t)s;
    tf2x32(0u, 42u, fk0, fk1);
    float* xo = (((STEPS - 1 - s) & 1) != 0) ? ws_x : out;

    nca_stats<<<NROW, 256, 0, stream>>>(xin, p0w, p0b, ws_part, ws_ybf);
    nca_reduceA<<<NSTAT, 256, 0, stream>>>(ws_part, ws_sred);
    nca_reduceB<<<1, 128, 0, stream>>>(ws_sred, fc0w, gamma, beta, ws_ss);
    nca_update_mfma<<<NCELLS / 1024, 256, 0, stream>>>(xin, ws_ybf, ws_w0bf,
                                                       ws_w1p, ws_ss, xo, fk0, fk1);
    xin = xo;
  }
}